// Round 7
// baseline (130.701 us; speedup 1.0000x reference)
//
#include <hip/hip_runtime.h>
#include <hip/hip_cooperative_groups.h>

// TimeNormalization: EMA scan over time + normalization.
//   s_t = 0.1*[x, x^2] + 0.9*s_{t-1}   (per (b,f), scan over t)
//   x_norm = (x - m) / sqrt(v - m^2 + 1e-3)
// Outputs concatenated: x_norm [B,T,F] then final_state [2,B,F].
//
// R1-R6 synthesis: duration == total L2-miss bytes / ~6.0 TB/s in every
// config -> only lever is bytes. This round: amp 1.25 -> 1.0 via a
// decoupled chunked scan. Key fact: 0.9^512 underflows f32, so chunk i's
// true incoming state == chunk i-1's zero-init local final EXACTLY.
// Phase 1: scan own chunk (stash first KH rows in LDS = zero fabric),
// write rows [KH,CL) (trunc err <= 0.9^129 ~ 1.3e-6), publish finals.
// grid.sync(). Phase 2: exact incoming state, re-scan [0,KH) from LDS.
// Every x row read from HBM exactly once: 134+131 = 265 MB ~ 44 us.

namespace cg = cooperative_groups;

namespace {
constexpr int Bc = 16, Tc = 4096, Fc = 512;
constexpr int CL = 512;          // chunk length
constexpr int KH = 128;          // rows needing exact incoming state (0.9^128 ~ 1.4e-6)
constexpr int NCHUNK = Tc / CL;  // 8
constexpr int LANES = 128;       // threads/block = f-quarter
constexpr float ALPHA = 0.1f;
constexpr float OMA = 0.9f;
constexpr float EPS = 1e-3f;
}

__global__ __launch_bounds__(LANES, 2) void tn_coop(const float* __restrict__ x,
                                                    const float* __restrict__ state,
                                                    float* __restrict__ out,
                                                    float* __restrict__ ws) {
    __shared__ float stash[KH * LANES];    // 64 KB, thread-private columns (conflict-free)

    // block = (b, chunk, fq); grid = 16*8*4 = 512 = exactly 2 blocks/CU co-resident
    const int fq = blockIdx.x & 3;
    const int chunk = (blockIdx.x >> 2) & (NCHUNK - 1);
    const int b = blockIdx.x >> 5;
    const int f = fq * LANES + threadIdx.x;
    const int t0 = chunk * CL;

    const size_t base = ((size_t)b * Tc + t0) * Fc + f;
    const float* xp = x + base;
    float* op = out + base;

    // ---- Phase 1: local scan (zero-init; chunk 0 exact) ----
    float s_m, s_v;
    if (chunk == 0) {
        s_m = state[b * Fc + f];
        s_v = state[Bc * Fc + b * Fc + f];
    } else {
        s_m = 0.f;
        s_v = 0.f;
    }

#pragma unroll 16
    for (int i = 0; i < KH; ++i) {         // stash + scan, no output yet
        float xv = xp[(size_t)i * Fc];
        stash[i * LANES + threadIdx.x] = xv;
        float px = ALPHA * xv;
        s_m = fmaf(OMA, s_m, px);
        s_v = fmaf(OMA, s_v, px * xv);
    }
#pragma unroll 16
    for (int i = KH; i < CL; ++i) {        // scan + output (trunc err <= 0.9^129)
        float xv = xp[(size_t)i * Fc];
        float px = ALPHA * xv;
        s_m = fmaf(OMA, s_m, px);
        s_v = fmaf(OMA, s_v, px * xv);
        float var = fmaf(-s_m, s_m, s_v);
        float r = (xv - s_m) * rsqrtf(var + EPS);
        __builtin_nontemporal_store(r, &op[(size_t)i * Fc]);
    }

    // publish local final state (agent scope: crosses XCD L2s)
    const int widx = (b * NCHUNK + chunk) * Fc + f;
    __hip_atomic_store(&ws[widx], s_m, __ATOMIC_RELAXED, __HIP_MEMORY_SCOPE_AGENT);
    __hip_atomic_store(&ws[Bc * NCHUNK * Fc + widx], s_v, __ATOMIC_RELAXED, __HIP_MEMORY_SCOPE_AGENT);

    if (chunk == NCHUNK - 1) {
        // final_state [2,B,F]; missing correction is 0.9^512 * s_in == 0 in f32
        const size_t so = (size_t)Bc * Tc * Fc;
        out[so + (size_t)b * Fc + f] = s_m;
        out[so + (size_t)Bc * Fc + (size_t)b * Fc + f] = s_v;
    }

    cg::this_grid().sync();

    // ---- Phase 2: exact incoming state, fix up rows [0, KH) from LDS ----
    if (chunk == 0) {
        s_m = state[b * Fc + f];
        s_v = state[Bc * Fc + b * Fc + f];
    } else {
        const int pidx = (b * NCHUNK + chunk - 1) * Fc + f;
        s_m = __hip_atomic_load(&ws[pidx], __ATOMIC_RELAXED, __HIP_MEMORY_SCOPE_AGENT);
        s_v = __hip_atomic_load(&ws[Bc * NCHUNK * Fc + pidx], __ATOMIC_RELAXED, __HIP_MEMORY_SCOPE_AGENT);
    }
#pragma unroll 16
    for (int i = 0; i < KH; ++i) {
        float xv = stash[i * LANES + threadIdx.x];
        float px = ALPHA * xv;
        s_m = fmaf(OMA, s_m, px);
        s_v = fmaf(OMA, s_v, px * xv);
        float var = fmaf(-s_m, s_m, s_v);
        float r = (xv - s_m) * rsqrtf(var + EPS);
        __builtin_nontemporal_store(r, &op[(size_t)i * Fc]);
    }
}

// ---- Fallback (R6 halo kernel) if ws_size is too small ----
__global__ __launch_bounds__(256) void tn_halo(const float* __restrict__ x,
                                               const float* __restrict__ state,
                                               float* __restrict__ out) {
    const int bid = blockIdx.x;            // grid = B * NCHUNK * 2 = 256
    const int fh = bid & 1;
    const int chunk = (bid >> 1) & (NCHUNK - 1);
    const int b = bid >> 4;
    const int f = fh * 256 + threadIdx.x;
    const int t0 = chunk * CL;

    const size_t base = ((size_t)b * Tc + t0) * Fc + f;
    const float* xp = x + base;

    float s_m, s_v;
    if (chunk == 0) {
        s_m = state[b * Fc + f];
        s_v = state[Bc * Fc + b * Fc + f];
    } else {
        s_m = 0.f;
        s_v = 0.f;
        const float* wp = xp - (size_t)KH * Fc;
#pragma unroll 16
        for (int i = 0; i < KH; ++i) {
            float xv = wp[(size_t)i * Fc];
            float px = ALPHA * xv;
            s_m = fmaf(OMA, s_m, px);
            s_v = fmaf(OMA, s_v, px * xv);
        }
    }

    float* op = out + base;
#pragma unroll 16
    for (int i = 0; i < CL; ++i) {
        float xv = xp[(size_t)i * Fc];
        float px = ALPHA * xv;
        s_m = fmaf(OMA, s_m, px);
        s_v = fmaf(OMA, s_v, px * xv);
        float var = fmaf(-s_m, s_m, s_v);
        float r = (xv - s_m) * rsqrtf(var + EPS);
        __builtin_nontemporal_store(r, &op[(size_t)i * Fc]);
    }

    if (chunk == NCHUNK - 1) {
        const size_t so = (size_t)Bc * Tc * Fc;
        out[so + (size_t)b * Fc + f] = s_m;
        out[so + (size_t)Bc * Fc + (size_t)b * Fc + f] = s_v;
    }
}

extern "C" void kernel_launch(void* const* d_in, const int* in_sizes, int n_in,
                              void* d_out, int out_size, void* d_ws, size_t ws_size,
                              hipStream_t stream) {
    const float* x = (const float*)d_in[0];      // [B,T,F] f32
    const float* st = (const float*)d_in[1];     // [2,B,F] f32
    float* out = (float*)d_out;                  // x_norm + final_state
    float* ws = (float*)d_ws;

    const size_t ws_needed = (size_t)2 * Bc * NCHUNK * Fc * sizeof(float);  // 512 KB
    if (ws_size >= ws_needed) {
        void* args[] = {(void*)&x, (void*)&st, (void*)&out, (void*)&ws};
        hipLaunchCooperativeKernel((const void*)tn_coop, dim3(Bc * NCHUNK * 4),
                                   dim3(LANES), args, 0, stream);
    } else {
        tn_halo<<<dim3(Bc * NCHUNK * 2), dim3(256), 0, stream>>>(x, st, out);
    }
}

// Round 8
// 63.866 us; speedup vs baseline: 2.0465x; 2.0465x over previous
//
#include <hip/hip_runtime.h>

// TimeNormalization: EMA scan over time + normalization.
//   s_t = 0.1*[x, x^2] + 0.9*s_{t-1}   (per (b,f), scan over t)
//   x_norm = (x - m) / sqrt(v - m^2 + 1e-3)
// Outputs concatenated: x_norm [B,T,F] then final_state [2,B,F].
//
// Standing model (R1-R6): bench time == total L2-miss bytes / ~5.96 TB/s
// in every config; grid-sync dedup (R7) costs >> the halo bytes it saves.
// Only lever: halo amplification = 1 + KH/CL (chunk 0 exact, no halo).
// This round: CL=1024 (NCHUNK=4) -> halo 29.4 -> 12.6 MB, 278 MB total.
// 512 blocks x 64 thr = 2 waves/CU; deep unroll + 1-wave blocks let the
// compiler hoist 16-32 loads/wave to cover HBM latency at low occupancy.
// KH=128 accuracy-pinned (0.9^128 ~ 1.4e-6 truncation).

namespace {
constexpr int Bc = 16, Tc = 4096, Fc = 512;
constexpr int CL = 1024;         // chunk length (amp = 1 + KH/CL = 1.125)
constexpr int KH = 128;          // halo (accuracy-critical, don't shrink)
constexpr int NCHUNK = Tc / CL;  // 4
constexpr int LANES = 64;        // 1 wave per block
constexpr float ALPHA = 0.1f;
constexpr float OMA = 0.9f;
constexpr float EPS = 1e-3f;
}

__global__ __launch_bounds__(64) void tn_kernel(const float* __restrict__ x,
                                                const float* __restrict__ state,
                                                float* __restrict__ out) {
    // grid = B * NCHUNK * (F/64) = 16*4*8 = 512 one-wave blocks (2 waves/CU)
    const int fg = blockIdx.x & 7;                 // f-group (fastest: coalesced neighbors)
    const int chunk = (blockIdx.x >> 3) & (NCHUNK - 1);
    const int b = blockIdx.x >> 5;
    const int f = fg * LANES + threadIdx.x;        // coalesced feature index
    const int t0 = chunk * CL;

    const size_t base = ((size_t)b * Tc + t0) * Fc + f;
    const float* xp = x + base;

    float s_m, s_v;
    if (chunk == 0) {
        // exact initial state: state[0,b,f] (mean), state[1,b,f] (mean-square)
        s_m = state[b * Fc + f];
        s_v = state[Bc * Fc + b * Fc + f];
    } else {
        // halo warmup; truncated history contributes <= 0.9^KH ~ 1.4e-6
        s_m = 0.f;
        s_v = 0.f;
        const float* wp = xp - (size_t)KH * Fc;
#pragma unroll 32
        for (int i = 0; i < KH; ++i) {
            float xv = wp[(size_t)i * Fc];
            float px = ALPHA * xv;
            s_m = fmaf(OMA, s_m, px);
            s_v = fmaf(OMA, s_v, px * xv);
        }
    }

    float* op = out + base;
#pragma unroll 32
    for (int i = 0; i < CL; ++i) {
        float xv = xp[(size_t)i * Fc];
        float px = ALPHA * xv;
        s_m = fmaf(OMA, s_m, px);
        s_v = fmaf(OMA, s_v, px * xv);
        float var = fmaf(-s_m, s_m, s_v);          // v - m^2
        float r = (xv - s_m) * rsqrtf(var + EPS);
        __builtin_nontemporal_store(r, &op[(size_t)i * Fc]);  // write-once stream
    }

    if (chunk == NCHUNK - 1) {
        // final_state [2,B,F] appended after x_norm
        const size_t so = (size_t)Bc * Tc * Fc;
        out[so + (size_t)b * Fc + f] = s_m;
        out[so + (size_t)Bc * Fc + (size_t)b * Fc + f] = s_v;
    }
}

extern "C" void kernel_launch(void* const* d_in, const int* in_sizes, int n_in,
                              void* d_out, int out_size, void* d_ws, size_t ws_size,
                              hipStream_t stream) {
    const float* x = (const float*)d_in[0];      // [B,T,F] f32
    const float* st = (const float*)d_in[1];     // [2,B,F] f32
    float* out = (float*)d_out;                  // x_norm + final_state

    dim3 grid(Bc * NCHUNK * (Fc / LANES));       // 512
    dim3 block(LANES);                           // 64 = 1 wave
    tn_kernel<<<grid, block, 0, stream>>>(x, st, out);
}